// Round 2
// baseline (679.132 us; speedup 1.0000x reference)
//
#include <hip/hip_runtime.h>

// GraphSAGE 3-layer (mean agg), N=100000 nodes, E=1600000 edges, 128->32->32->16.
// Round 2: project-then-aggregate + CSR gather (no float atomics).
// CSR is rebuilt every call (deterministic work; segment order is atomic-raced but
// summation noise << threshold, same class as round-1's atomics which passed).

#define BLOCK 256

// ---------------- degree (int atomics) ----------------
__global__ void degree_kernel(const int* __restrict__ dst, int* __restrict__ deg, int n_edges) {
    int e = blockIdx.x * blockDim.x + threadIdx.x;
    if (e < n_edges) atomicAdd(&deg[dst[e]], 1);
}

// ---------------- single-block exclusive scan over degrees ----------------
// 1024 threads, each owns a contiguous chunk; Hillis-Steele on partials.
__global__ void scan_kernel(const int* __restrict__ deg,
                            int* __restrict__ start,
                            float* __restrict__ invdeg,
                            int n_nodes) {
    __shared__ int partial[1024];
    int tid = threadIdx.x;
    int chunk = (n_nodes + 1023) >> 10;
    int lo = tid * chunk;
    int hi = lo + chunk; if (hi > n_nodes) hi = n_nodes;
    int s = 0;
    for (int i = lo; i < hi; ++i) s += deg[i];
    partial[tid] = s;
    __syncthreads();
    for (int off = 1; off < 1024; off <<= 1) {
        int v = (tid >= off) ? partial[tid - off] : 0;
        __syncthreads();
        partial[tid] += v;
        __syncthreads();
    }
    int run = (tid > 0) ? partial[tid - 1] : 0;
    for (int i = lo; i < hi; ++i) {
        start[i] = run;
        int d = deg[i];
        invdeg[i] = 1.0f / (float)(d < 1 ? 1 : d);
        run += d;
    }
    if (tid == 1023) start[n_nodes] = partial[1023];
}

// ---------------- CSR fill: csr_src[start[dst]+rank] = src ----------------
__global__ void fill_kernel(const int* __restrict__ src, const int* __restrict__ dst,
                            const int* __restrict__ start, int* __restrict__ cursor,
                            int* __restrict__ csr_src, int n_edges) {
    int e = blockIdx.x * blockDim.x + threadIdx.x;
    if (e >= n_edges) return;
    int d = dst[e];
    int slot = start[d] + atomicAdd(&cursor[d], 1);
    csr_src[slot] = src[e];
}

// ---------------- fused projection: pre = h@Wself + b ; p = h@Wneigh ----------------
template<int DIN, int DOUT>
__global__ void proj_kernel(const float* __restrict__ h,
                            const float* __restrict__ Wself,
                            const float* __restrict__ Wneigh,
                            const float* __restrict__ bias,
                            float* __restrict__ pre,
                            float* __restrict__ p,
                            int n_nodes) {
    __shared__ float sWs[DIN * DOUT];
    __shared__ float sWn[DIN * DOUT];
    __shared__ float sb[DOUT];
    for (int i = threadIdx.x; i < DIN * DOUT; i += blockDim.x) {
        sWs[i] = Wself[i];
        sWn[i] = Wneigh[i];
    }
    if (threadIdx.x < DOUT) sb[threadIdx.x] = bias[threadIdx.x];
    __syncthreads();

    int idx = blockIdx.x * blockDim.x + threadIdx.x;   // over n_nodes * DOUT
    int node = idx / DOUT;
    int f    = idx % DOUT;
    if (node >= n_nodes) return;

    const float* __restrict__ row = h + (size_t)node * DIN;
    float accS = 0.f, accN = 0.f;
#pragma unroll 8
    for (int k = 0; k < DIN; ++k) {
        float x = row[k];
        accS = fmaf(x, sWs[k * DOUT + f], accS);
        accN = fmaf(x, sWn[k * DOUT + f], accN);
    }
    pre[idx] = accS + sb[f];
    p[idx]   = accN;
}

// ---------------- fused gather + finalize: out = act(pre + mean_neigh(p)) ----------------
template<int D, bool RELU>
__global__ void gather_kernel(const float* __restrict__ p,
                              const int* __restrict__ csr_src,
                              const int* __restrict__ start,
                              const float* __restrict__ pre,
                              const float* __restrict__ invdeg,
                              float* __restrict__ out,
                              int n_nodes) {
    int g = blockIdx.x * (blockDim.x / D) + threadIdx.x / D;   // node
    int f = threadIdx.x % D;                                    // feature
    if (g >= n_nodes) return;
    int s0 = start[g];
    int s1 = start[g + 1];
    float a0 = 0.f, a1 = 0.f;
    int j = s0;
    for (; j + 1 < s1; j += 2) {
        int c0 = csr_src[j];
        int c1 = csr_src[j + 1];
        a0 += p[(size_t)c0 * D + f];
        a1 += p[(size_t)c1 * D + f];
    }
    if (j < s1) a0 += p[(size_t)csr_src[j] * D + f];
    size_t o = (size_t)g * D + f;
    float v = pre[o] + (a0 + a1) * invdeg[g];
    if (RELU) v = fmaxf(v, 0.f);
    out[o] = v;
}

extern "C" void kernel_launch(void* const* d_in, const int* in_sizes, int n_in,
                              void* d_out, int out_size, void* d_ws, size_t ws_size,
                              hipStream_t stream) {
    const float* x        = (const float*)d_in[0];
    const int*   edge_src = (const int*)d_in[1];
    const int*   edge_dst = (const int*)d_in[2];
    const float* Ws1 = (const float*)d_in[3];
    const float* Wn1 = (const float*)d_in[4];
    const float* b1  = (const float*)d_in[5];
    const float* Ws2 = (const float*)d_in[6];
    const float* Wn2 = (const float*)d_in[7];
    const float* b2  = (const float*)d_in[8];
    const float* Ws3 = (const float*)d_in[9];
    const float* Wn3 = (const float*)d_in[10];
    const float* b3  = (const float*)d_in[11];
    float* out = (float*)d_out;

    const int IN = 128, HID = 32;
    const int n_nodes = in_sizes[0] / IN;
    const int n_edges = in_sizes[1];

    // ---- workspace layout ----
    char* wsb = (char*)d_ws;
    size_t off = 0;
    auto alloc = [&](size_t bytes) { char* r = wsb + off; off = (off + bytes + 255) & ~(size_t)255; return r; };
    int*   deg    = (int*)alloc((size_t)n_nodes * sizeof(int));
    int*   cursor = (int*)alloc((size_t)n_nodes * sizeof(int));
    int*   startp = (int*)alloc(((size_t)n_nodes + 1) * sizeof(int));
    float* invdeg = (float*)alloc((size_t)n_nodes * sizeof(float));
    int*   csr    = (int*)alloc((size_t)n_edges * sizeof(int));
    float* B0     = (float*)alloc((size_t)n_nodes * HID * sizeof(float));  // pre
    float* B1     = (float*)alloc((size_t)n_nodes * HID * sizeof(float));  // p
    float* B3     = (float*)alloc((size_t)n_nodes * HID * sizeof(float));  // h

    const int gEdges = (n_edges + BLOCK - 1) / BLOCK;
    const int gN32   = ((size_t)n_nodes * 32 + BLOCK - 1) / BLOCK;
    const int gN16   = ((size_t)n_nodes * 16 + BLOCK - 1) / BLOCK;
    const int gGat32 = (n_nodes + (BLOCK / 32) - 1) / (BLOCK / 32);
    const int gGat16 = (n_nodes + (BLOCK / 16) - 1) / (BLOCK / 16);

    // ---- CSR build (once per call) ----
    hipMemsetAsync(deg, 0, (size_t)n_nodes * sizeof(int), stream);
    hipMemsetAsync(cursor, 0, (size_t)n_nodes * sizeof(int), stream);
    degree_kernel<<<gEdges, BLOCK, 0, stream>>>(edge_dst, deg, n_edges);
    scan_kernel<<<1, 1024, 0, stream>>>(deg, startp, invdeg, n_nodes);
    fill_kernel<<<gEdges, BLOCK, 0, stream>>>(edge_src, edge_dst, startp, cursor, csr, n_edges);

    // ---- layer 1: 128 -> 32, relu ----
    proj_kernel<128, 32><<<gN32, BLOCK, 0, stream>>>(x, Ws1, Wn1, b1, B0, B1, n_nodes);
    gather_kernel<32, true><<<gGat32, BLOCK, 0, stream>>>(B1, csr, startp, B0, invdeg, B3, n_nodes);

    // ---- layer 2: 32 -> 32, relu ----
    proj_kernel<32, 32><<<gN32, BLOCK, 0, stream>>>(B3, Ws2, Wn2, b2, B0, B1, n_nodes);
    gather_kernel<32, true><<<gGat32, BLOCK, 0, stream>>>(B1, csr, startp, B0, invdeg, B3, n_nodes);

    // ---- layer 3: 32 -> 16, no relu ----
    proj_kernel<32, 16><<<gN16, BLOCK, 0, stream>>>(B3, Ws3, Wn3, b3, B0, B1, n_nodes);
    gather_kernel<16, false><<<gGat16, BLOCK, 0, stream>>>(B1, csr, startp, B0, invdeg, out, n_nodes);
}

// Round 3
// 444.742 us; speedup vs baseline: 1.5270x; 1.5270x over previous
//
#include <hip/hip_runtime.h>

// GraphSAGE 3-layer (mean agg), N=100000, E=1600000, 128->32->32->16.
// Round 3: CSR gather (no float atomics) + parallel 3-phase scan
// (round 2's single-block scan was 230us of serial latency on one CU).

#define BLOCK 256

// ---------------- degree (int atomics) ----------------
__global__ void degree_kernel(const int* __restrict__ dst, int* __restrict__ deg, int n_edges) {
    int e = blockIdx.x * blockDim.x + threadIdx.x;
    if (e < n_edges) atomicAdd(&deg[dst[e]], 1);
}

// ---------------- scan phase A: per-block sums of deg ----------------
__global__ void scanA_kernel(const int* __restrict__ deg, int* __restrict__ bsum, int n_nodes) {
    int i = blockIdx.x * blockDim.x + threadIdx.x;
    int d = (i < n_nodes) ? deg[i] : 0;
    // wave reduce
    int v = d;
    for (int off = 32; off > 0; off >>= 1) v += __shfl_down(v, off);
    __shared__ int wsum[BLOCK / 64];
    int lane = threadIdx.x & 63, wv = threadIdx.x >> 6;
    if (lane == 0) wsum[wv] = v;
    __syncthreads();
    if (threadIdx.x == 0) {
        int s = 0;
        for (int w = 0; w < BLOCK / 64; ++w) s += wsum[w];
        bsum[blockIdx.x] = s;
    }
}

// ---------------- scan phase B: exclusive scan of block sums (1 small block) ----------------
__global__ void scanB_kernel(int* __restrict__ bsum, int* __restrict__ boff,
                             int* __restrict__ start_last, int nblocks) {
    __shared__ int sh[1024];
    int tid = threadIdx.x;
    sh[tid] = (tid < nblocks) ? bsum[tid] : 0;
    __syncthreads();
    for (int off = 1; off < 1024; off <<= 1) {
        int v = (tid >= off) ? sh[tid - off] : 0;
        __syncthreads();
        sh[tid] += v;
        __syncthreads();
    }
    if (tid < nblocks) boff[tid] = sh[tid] - bsum[tid];   // exclusive
    if (tid == 1023) *start_last = sh[1023];              // total edges
}

// ---------------- scan phase C: in-block exclusive scan + invdeg ----------------
__global__ void scanC_kernel(const int* __restrict__ deg, const int* __restrict__ boff,
                             int* __restrict__ start, float* __restrict__ invdeg, int n_nodes) {
    int tid = threadIdx.x;
    int i = blockIdx.x * blockDim.x + tid;
    int d = (i < n_nodes) ? deg[i] : 0;
    int lane = tid & 63, wv = tid >> 6;
    int v = d;
    for (int off = 1; off < 64; off <<= 1) {
        int u = __shfl_up(v, off);
        if (lane >= off) v += u;
    }
    __shared__ int wsum[BLOCK / 64];
    if (lane == 63) wsum[wv] = v;
    __syncthreads();
    int wadd = 0;
    for (int w = 0; w < wv; ++w) wadd += wsum[w];
    int excl = v - d + wadd + boff[blockIdx.x];
    if (i < n_nodes) {
        start[i] = excl;
        invdeg[i] = 1.0f / (float)(d < 1 ? 1 : d);
    }
}

// ---------------- CSR fill: csr_src[start[dst]+rank] = src ----------------
__global__ void fill_kernel(const int* __restrict__ src, const int* __restrict__ dst,
                            const int* __restrict__ start, int* __restrict__ cursor,
                            int* __restrict__ csr_src, int n_edges) {
    int e = blockIdx.x * blockDim.x + threadIdx.x;
    if (e >= n_edges) return;
    int d = dst[e];
    int slot = start[d] + atomicAdd(&cursor[d], 1);
    csr_src[slot] = src[e];
}

// ---------------- fused projection: pre = h@Wself + b ; p = h@Wneigh ----------------
template<int DIN, int DOUT>
__global__ void proj_kernel(const float* __restrict__ h,
                            const float* __restrict__ Wself,
                            const float* __restrict__ Wneigh,
                            const float* __restrict__ bias,
                            float* __restrict__ pre,
                            float* __restrict__ p,
                            int n_nodes) {
    __shared__ float sWs[DIN * DOUT];
    __shared__ float sWn[DIN * DOUT];
    __shared__ float sb[DOUT];
    for (int i = threadIdx.x; i < DIN * DOUT; i += blockDim.x) {
        sWs[i] = Wself[i];
        sWn[i] = Wneigh[i];
    }
    if (threadIdx.x < DOUT) sb[threadIdx.x] = bias[threadIdx.x];
    __syncthreads();

    int idx = blockIdx.x * blockDim.x + threadIdx.x;   // over n_nodes * DOUT
    int node = idx / DOUT;
    int f    = idx % DOUT;
    if (node >= n_nodes) return;

    const float* __restrict__ row = h + (size_t)node * DIN;
    float accS = 0.f, accN = 0.f;
#pragma unroll 8
    for (int k = 0; k < DIN; ++k) {
        float x = row[k];
        accS = fmaf(x, sWs[k * DOUT + f], accS);
        accN = fmaf(x, sWn[k * DOUT + f], accN);
    }
    pre[idx] = accS + sb[f];
    p[idx]   = accN;
}

// ---------------- fused gather + finalize: out = act(pre + mean_neigh(p)) ----------------
template<int D, bool RELU>
__global__ void gather_kernel(const float* __restrict__ p,
                              const int* __restrict__ csr_src,
                              const int* __restrict__ start,
                              const float* __restrict__ pre,
                              const float* __restrict__ invdeg,
                              float* __restrict__ out,
                              int n_nodes) {
    int g = blockIdx.x * (blockDim.x / D) + threadIdx.x / D;   // node
    int f = threadIdx.x % D;                                    // feature
    if (g >= n_nodes) return;
    int s0 = start[g];
    int s1 = start[g + 1];
    float a0 = 0.f, a1 = 0.f;
    int j = s0;
    for (; j + 1 < s1; j += 2) {
        int c0 = csr_src[j];
        int c1 = csr_src[j + 1];
        a0 += p[(size_t)c0 * D + f];
        a1 += p[(size_t)c1 * D + f];
    }
    if (j < s1) a0 += p[(size_t)csr_src[j] * D + f];
    size_t o = (size_t)g * D + f;
    float v = pre[o] + (a0 + a1) * invdeg[g];
    if (RELU) v = fmaxf(v, 0.f);
    out[o] = v;
}

extern "C" void kernel_launch(void* const* d_in, const int* in_sizes, int n_in,
                              void* d_out, int out_size, void* d_ws, size_t ws_size,
                              hipStream_t stream) {
    const float* x        = (const float*)d_in[0];
    const int*   edge_src = (const int*)d_in[1];
    const int*   edge_dst = (const int*)d_in[2];
    const float* Ws1 = (const float*)d_in[3];
    const float* Wn1 = (const float*)d_in[4];
    const float* b1  = (const float*)d_in[5];
    const float* Ws2 = (const float*)d_in[6];
    const float* Wn2 = (const float*)d_in[7];
    const float* b2  = (const float*)d_in[8];
    const float* Ws3 = (const float*)d_in[9];
    const float* Wn3 = (const float*)d_in[10];
    const float* b3  = (const float*)d_in[11];
    float* out = (float*)d_out;

    const int IN = 128, HID = 32;
    const int n_nodes = in_sizes[0] / IN;
    const int n_edges = in_sizes[1];

    // ---- workspace layout ----
    char* wsb = (char*)d_ws;
    size_t off = 0;
    auto alloc = [&](size_t bytes) { char* r = wsb + off; off = (off + bytes + 255) & ~(size_t)255; return r; };
    int*   deg    = (int*)alloc((size_t)n_nodes * sizeof(int));
    int*   cursor = (int*)alloc((size_t)n_nodes * sizeof(int));
    int*   startp = (int*)alloc(((size_t)n_nodes + 1) * sizeof(int));
    float* invdeg = (float*)alloc((size_t)n_nodes * sizeof(float));
    int*   csr    = (int*)alloc((size_t)n_edges * sizeof(int));
    int*   bsum   = (int*)alloc(1024 * sizeof(int));
    int*   boff   = (int*)alloc(1024 * sizeof(int));
    float* B0     = (float*)alloc((size_t)n_nodes * HID * sizeof(float));  // pre
    float* B1     = (float*)alloc((size_t)n_nodes * HID * sizeof(float));  // p
    float* B3     = (float*)alloc((size_t)n_nodes * HID * sizeof(float));  // h

    const int gEdges = (n_edges + BLOCK - 1) / BLOCK;
    const int gNodes = (n_nodes + BLOCK - 1) / BLOCK;     // = scan blocks (<=1024)
    const int gN32   = ((size_t)n_nodes * 32 + BLOCK - 1) / BLOCK;
    const int gN16   = ((size_t)n_nodes * 16 + BLOCK - 1) / BLOCK;
    const int gGat32 = (n_nodes + (BLOCK / 32) - 1) / (BLOCK / 32);
    const int gGat16 = (n_nodes + (BLOCK / 16) - 1) / (BLOCK / 16);

    // ---- CSR build (once per call) ----
    hipMemsetAsync(deg, 0, (size_t)n_nodes * sizeof(int), stream);
    hipMemsetAsync(cursor, 0, (size_t)n_nodes * sizeof(int), stream);
    degree_kernel<<<gEdges, BLOCK, 0, stream>>>(edge_dst, deg, n_edges);
    scanA_kernel<<<gNodes, BLOCK, 0, stream>>>(deg, bsum, n_nodes);
    scanB_kernel<<<1, 1024, 0, stream>>>(bsum, boff, startp + n_nodes, gNodes);
    scanC_kernel<<<gNodes, BLOCK, 0, stream>>>(deg, boff, startp, invdeg, n_nodes);
    fill_kernel<<<gEdges, BLOCK, 0, stream>>>(edge_src, edge_dst, startp, cursor, csr, n_edges);

    // ---- layer 1: 128 -> 32, relu ----
    proj_kernel<128, 32><<<gN32, BLOCK, 0, stream>>>(x, Ws1, Wn1, b1, B0, B1, n_nodes);
    gather_kernel<32, true><<<gGat32, BLOCK, 0, stream>>>(B1, csr, startp, B0, invdeg, B3, n_nodes);

    // ---- layer 2: 32 -> 32, relu ----
    proj_kernel<32, 32><<<gN32, BLOCK, 0, stream>>>(B3, Ws2, Wn2, b2, B0, B1, n_nodes);
    gather_kernel<32, true><<<gGat32, BLOCK, 0, stream>>>(B1, csr, startp, B0, invdeg, B3, n_nodes);

    // ---- layer 3: 32 -> 16, no relu ----
    proj_kernel<32, 16><<<gN16, BLOCK, 0, stream>>>(B3, Ws3, Wn3, b3, B0, B1, n_nodes);
    gather_kernel<16, false><<<gGat16, BLOCK, 0, stream>>>(B1, csr, startp, B0, invdeg, out, n_nodes);
}

// Round 4
// 379.054 us; speedup vs baseline: 1.7917x; 1.1733x over previous
//
#include <hip/hip_runtime.h>

// GraphSAGE 3-layer (mean agg), N=100000, E=1600000, 128->32->32->16.
// Round 4: register-tiled f32 projection GEMM (4 nodes x 8 outs per thread,
// x staged in LDS k-chunks) replacing the 1-output-per-thread proj that was
// latency-bound at 33% VALUBusy. CSR gather unchanged.

#define BLOCK 256

// ---------------- degree (int atomics) ----------------
__global__ void degree_kernel(const int* __restrict__ dst, int* __restrict__ deg, int n_edges) {
    int e = blockIdx.x * blockDim.x + threadIdx.x;
    if (e < n_edges) atomicAdd(&deg[dst[e]], 1);
}

// ---------------- scan phase A: per-block sums of deg ----------------
__global__ void scanA_kernel(const int* __restrict__ deg, int* __restrict__ bsum, int n_nodes) {
    int i = blockIdx.x * blockDim.x + threadIdx.x;
    int d = (i < n_nodes) ? deg[i] : 0;
    int v = d;
    for (int off = 32; off > 0; off >>= 1) v += __shfl_down(v, off);
    __shared__ int wsum[BLOCK / 64];
    int lane = threadIdx.x & 63, wv = threadIdx.x >> 6;
    if (lane == 0) wsum[wv] = v;
    __syncthreads();
    if (threadIdx.x == 0) {
        int s = 0;
        for (int w = 0; w < BLOCK / 64; ++w) s += wsum[w];
        bsum[blockIdx.x] = s;
    }
}

// ---------------- scan phase B: exclusive scan of block sums ----------------
__global__ void scanB_kernel(int* __restrict__ bsum, int* __restrict__ boff,
                             int* __restrict__ start_last, int nblocks) {
    __shared__ int sh[1024];
    int tid = threadIdx.x;
    sh[tid] = (tid < nblocks) ? bsum[tid] : 0;
    __syncthreads();
    for (int off = 1; off < 1024; off <<= 1) {
        int v = (tid >= off) ? sh[tid - off] : 0;
        __syncthreads();
        sh[tid] += v;
        __syncthreads();
    }
    if (tid < nblocks) boff[tid] = sh[tid] - bsum[tid];
    if (tid == 1023) *start_last = sh[1023];
}

// ---------------- scan phase C: in-block exclusive scan + invdeg + cursor=0 ----------------
__global__ void scanC_kernel(const int* __restrict__ deg, const int* __restrict__ boff,
                             int* __restrict__ start, float* __restrict__ invdeg,
                             int* __restrict__ cursor, int n_nodes) {
    int tid = threadIdx.x;
    int i = blockIdx.x * blockDim.x + tid;
    int d = (i < n_nodes) ? deg[i] : 0;
    int lane = tid & 63, wv = tid >> 6;
    int v = d;
    for (int off = 1; off < 64; off <<= 1) {
        int u = __shfl_up(v, off);
        if (lane >= off) v += u;
    }
    __shared__ int wsum[BLOCK / 64];
    if (lane == 63) wsum[wv] = v;
    __syncthreads();
    int wadd = 0;
    for (int w = 0; w < wv; ++w) wadd += wsum[w];
    int excl = v - d + wadd + boff[blockIdx.x];
    if (i < n_nodes) {
        start[i] = excl;
        invdeg[i] = 1.0f / (float)(d < 1 ? 1 : d);
        cursor[i] = 0;
    }
}

// ---------------- CSR fill ----------------
__global__ void fill_kernel(const int* __restrict__ src, const int* __restrict__ dst,
                            const int* __restrict__ start, int* __restrict__ cursor,
                            int* __restrict__ csr_src, int n_edges) {
    int e = blockIdx.x * blockDim.x + threadIdx.x;
    if (e >= n_edges) return;
    int d = dst[e];
    int slot = start[d] + atomicAdd(&cursor[d], 1);
    csr_src[slot] = src[e];
}

// ---------------- register-tiled projection: pre = h@Ws + b ; p = h@Wn ----------------
// Block = 256 threads, tile = NT nodes x OD outputs (OD = 2*DOUT, self|neigh).
// Per thread: 4 nodes x 8 outputs = 32 accumulators.
template<int DIN, int DOUT>
__global__ __launch_bounds__(256, 2)
void proj_tiled(const float* __restrict__ h,
                const float* __restrict__ Ws,
                const float* __restrict__ Wn,
                const float* __restrict__ bias,
                float* __restrict__ pre,
                float* __restrict__ p,
                int n_nodes) {
    constexpr int OD  = 2 * DOUT;       // 64 or 32
    constexpr int OPT = 8;              // outputs per thread
    constexpr int OG  = OD / OPT;       // output groups (8 or 4)
    constexpr int NPT = 4;              // nodes per thread
    constexpr int NG  = 256 / OG;       // node groups (32 or 64)
    constexpr int NT  = NPT * NG;       // node tile (128 or 256)
    constexpr int KC  = 32;             // k chunk
    constexpr int NCH = DIN / KC;

    __shared__ float sW[DIN][OD];
    __shared__ float sx[NT][KC + 1];
    __shared__ float sb[DOUT];

    const int tid = threadIdx.x;
    for (int i = tid; i < DIN * OD; i += 256) {
        int k = i / OD, o = i % OD;
        sW[k][o] = (o < DOUT) ? Ws[k * DOUT + o] : Wn[k * DOUT + (o - DOUT)];
    }
    if (tid < DOUT) sb[tid] = bias[tid];

    const int to = tid % OG;
    const int tn = tid / OG;
    const int o0 = to * OPT;
    const int node0 = blockIdx.x * NT;

    float acc[NPT][OPT];
#pragma unroll
    for (int n = 0; n < NPT; ++n)
#pragma unroll
        for (int o = 0; o < OPT; ++o) acc[n][o] = 0.f;

    constexpr int L4 = NT * KC / (256 * 4);   // float4 stage loads per thread
    for (int c = 0; c < NCH; ++c) {
        if (c > 0) __syncthreads();           // protect sx before overwrite
        // stage x chunk (coalesced): sx[node][k] = h[node0+node][c*KC+k]
#pragma unroll
        for (int q = 0; q < L4; ++q) {
            int fq   = q * 256 + tid;
            int node = fq / (KC / 4);
            int kq   = fq % (KC / 4);
            float4 v = make_float4(0.f, 0.f, 0.f, 0.f);
            int gn = node0 + node;
            if (gn < n_nodes)
                v = *reinterpret_cast<const float4*>(h + (size_t)gn * DIN + c * KC + kq * 4);
            sx[node][kq * 4 + 0] = v.x;
            sx[node][kq * 4 + 1] = v.y;
            sx[node][kq * 4 + 2] = v.z;
            sx[node][kq * 4 + 3] = v.w;
        }
        __syncthreads();

#pragma unroll 8
        for (int k = 0; k < KC; ++k) {
            const float4 wa = *reinterpret_cast<const float4*>(&sW[c * KC + k][o0]);
            const float4 wb = *reinterpret_cast<const float4*>(&sW[c * KC + k][o0 + 4]);
            float xv[NPT];
#pragma unroll
            for (int n = 0; n < NPT; ++n) xv[n] = sx[tn * NPT + n][k];
#pragma unroll
            for (int n = 0; n < NPT; ++n) {
                acc[n][0] = fmaf(xv[n], wa.x, acc[n][0]);
                acc[n][1] = fmaf(xv[n], wa.y, acc[n][1]);
                acc[n][2] = fmaf(xv[n], wa.z, acc[n][2]);
                acc[n][3] = fmaf(xv[n], wa.w, acc[n][3]);
                acc[n][4] = fmaf(xv[n], wb.x, acc[n][4]);
                acc[n][5] = fmaf(xv[n], wb.y, acc[n][5]);
                acc[n][6] = fmaf(xv[n], wb.z, acc[n][6]);
                acc[n][7] = fmaf(xv[n], wb.w, acc[n][7]);
            }
        }
    }

    const bool self_half = (o0 < DOUT);
#pragma unroll
    for (int n = 0; n < NPT; ++n) {
        int node = node0 + tn * NPT + n;
        if (node >= n_nodes) continue;
        if (self_half) {
            float4 r0 = make_float4(acc[n][0] + sb[o0 + 0], acc[n][1] + sb[o0 + 1],
                                    acc[n][2] + sb[o0 + 2], acc[n][3] + sb[o0 + 3]);
            float4 r1 = make_float4(acc[n][4] + sb[o0 + 4], acc[n][5] + sb[o0 + 5],
                                    acc[n][6] + sb[o0 + 6], acc[n][7] + sb[o0 + 7]);
            *reinterpret_cast<float4*>(pre + (size_t)node * DOUT + o0)     = r0;
            *reinterpret_cast<float4*>(pre + (size_t)node * DOUT + o0 + 4) = r1;
        } else {
            int oo = o0 - DOUT;
            float4 r0 = make_float4(acc[n][0], acc[n][1], acc[n][2], acc[n][3]);
            float4 r1 = make_float4(acc[n][4], acc[n][5], acc[n][6], acc[n][7]);
            *reinterpret_cast<float4*>(p + (size_t)node * DOUT + oo)     = r0;
            *reinterpret_cast<float4*>(p + (size_t)node * DOUT + oo + 4) = r1;
        }
    }
}

// ---------------- fused gather + finalize: out = act(pre + mean_neigh(p)) ----------------
template<int D, bool RELU>
__global__ void gather_kernel(const float* __restrict__ p,
                              const int* __restrict__ csr_src,
                              const int* __restrict__ start,
                              const float* __restrict__ pre,
                              const float* __restrict__ invdeg,
                              float* __restrict__ out,
                              int n_nodes) {
    int g = blockIdx.x * (blockDim.x / D) + threadIdx.x / D;
    int f = threadIdx.x % D;
    if (g >= n_nodes) return;
    int s0 = start[g];
    int s1 = start[g + 1];
    float a0 = 0.f, a1 = 0.f;
    int j = s0;
    for (; j + 1 < s1; j += 2) {
        int c0 = csr_src[j];
        int c1 = csr_src[j + 1];
        a0 += p[(size_t)c0 * D + f];
        a1 += p[(size_t)c1 * D + f];
    }
    if (j < s1) a0 += p[(size_t)csr_src[j] * D + f];
    size_t o = (size_t)g * D + f;
    float v = pre[o] + (a0 + a1) * invdeg[g];
    if (RELU) v = fmaxf(v, 0.f);
    out[o] = v;
}

extern "C" void kernel_launch(void* const* d_in, const int* in_sizes, int n_in,
                              void* d_out, int out_size, void* d_ws, size_t ws_size,
                              hipStream_t stream) {
    const float* x        = (const float*)d_in[0];
    const int*   edge_src = (const int*)d_in[1];
    const int*   edge_dst = (const int*)d_in[2];
    const float* Ws1 = (const float*)d_in[3];
    const float* Wn1 = (const float*)d_in[4];
    const float* b1  = (const float*)d_in[5];
    const float* Ws2 = (const float*)d_in[6];
    const float* Wn2 = (const float*)d_in[7];
    const float* b2  = (const float*)d_in[8];
    const float* Ws3 = (const float*)d_in[9];
    const float* Wn3 = (const float*)d_in[10];
    const float* b3  = (const float*)d_in[11];
    float* out = (float*)d_out;

    const int IN = 128, HID = 32;
    const int n_nodes = in_sizes[0] / IN;
    const int n_edges = in_sizes[1];

    char* wsb = (char*)d_ws;
    size_t off = 0;
    auto alloc = [&](size_t bytes) { char* r = wsb + off; off = (off + bytes + 255) & ~(size_t)255; return r; };
    int*   deg    = (int*)alloc((size_t)n_nodes * sizeof(int));
    int*   cursor = (int*)alloc((size_t)n_nodes * sizeof(int));
    int*   startp = (int*)alloc(((size_t)n_nodes + 1) * sizeof(int));
    float* invdeg = (float*)alloc((size_t)n_nodes * sizeof(float));
    int*   csr    = (int*)alloc((size_t)n_edges * sizeof(int));
    int*   bsum   = (int*)alloc(1024 * sizeof(int));
    int*   boff   = (int*)alloc(1024 * sizeof(int));
    float* B0     = (float*)alloc((size_t)n_nodes * HID * sizeof(float));  // pre
    float* B1     = (float*)alloc((size_t)n_nodes * HID * sizeof(float));  // p
    float* B3     = (float*)alloc((size_t)n_nodes * HID * sizeof(float));  // h

    const int gEdges = (n_edges + BLOCK - 1) / BLOCK;
    const int gNodes = (n_nodes + BLOCK - 1) / BLOCK;
    const int gP12   = (n_nodes + 127) / 128;   // proj_tiled NT=128
    const int gP3    = (n_nodes + 255) / 256;   // proj_tiled NT=256
    const int gGat32 = (n_nodes + (BLOCK / 32) - 1) / (BLOCK / 32);
    const int gGat16 = (n_nodes + (BLOCK / 16) - 1) / (BLOCK / 16);

    // ---- CSR build ----
    hipMemsetAsync(deg, 0, (size_t)n_nodes * sizeof(int), stream);
    degree_kernel<<<gEdges, BLOCK, 0, stream>>>(edge_dst, deg, n_edges);
    scanA_kernel<<<gNodes, BLOCK, 0, stream>>>(deg, bsum, n_nodes);
    scanB_kernel<<<1, 1024, 0, stream>>>(bsum, boff, startp + n_nodes, gNodes);
    scanC_kernel<<<gNodes, BLOCK, 0, stream>>>(deg, boff, startp, invdeg, cursor, n_nodes);
    fill_kernel<<<gEdges, BLOCK, 0, stream>>>(edge_src, edge_dst, startp, cursor, csr, n_edges);

    // ---- layer 1: 128 -> 32, relu ----
    proj_tiled<128, 32><<<gP12, BLOCK, 0, stream>>>(x, Ws1, Wn1, b1, B0, B1, n_nodes);
    gather_kernel<32, true><<<gGat32, BLOCK, 0, stream>>>(B1, csr, startp, B0, invdeg, B3, n_nodes);

    // ---- layer 2: 32 -> 32, relu ----
    proj_tiled<32, 32><<<gP12, BLOCK, 0, stream>>>(B3, Ws2, Wn2, b2, B0, B1, n_nodes);
    gather_kernel<32, true><<<gGat32, BLOCK, 0, stream>>>(B1, csr, startp, B0, invdeg, B3, n_nodes);

    // ---- layer 3: 32 -> 16, no relu ----
    proj_tiled<32, 16><<<gP3, BLOCK, 0, stream>>>(B3, Ws3, Wn3, b3, B0, B1, n_nodes);
    gather_kernel<16, false><<<gGat16, BLOCK, 0, stream>>>(B1, csr, startp, B0, invdeg, out, n_nodes);
}